// Round 4
// baseline (233.818 us; speedup 1.0000x reference)
//
#include <hip/hip_runtime.h>
#include <stdint.h>

#define B_ 4
#define S_ 2048
#define D_ 1024
#define H_ 16
#define DK_ 64
#define M_ (B_*S_)   // 8192

typedef __attribute__((ext_vector_type(8))) short short8;
typedef __attribute__((ext_vector_type(4))) float f32x4;
typedef __attribute__((ext_vector_type(16))) float f32x16;
typedef __attribute__((ext_vector_type(2))) unsigned int u32x2;

static __device__ __forceinline__ float bf2f(unsigned short s) {
  union { unsigned u; float f; } v; v.u = ((unsigned)s) << 16; return v.f;
}
static __device__ __forceinline__ unsigned short f2bf(float f) {
  union { float f; unsigned u; } v; v.f = f;
  unsigned r = v.u + 0x7fffu + ((v.u >> 16) & 1u);
  return (unsigned short)(r >> 16);
}
static __device__ __forceinline__ unsigned cvtpk_bf16(float lo, float hi) {
  unsigned r;
  asm("v_cvt_pk_bf16_f32 %0, %1, %2" : "=v"(r) : "v"(lo), "v"(hi));
  return r;
}

#define GLDS16(g, l) __builtin_amdgcn_global_load_lds( \
    (const __attribute__((address_space(1))) unsigned int*)(g), \
    (__attribute__((address_space(3))) unsigned int*)(l), 16, 0, 0)

// ---------------- fp32 -> bf16 convert (x) ----------------
__global__ void cvt_kernel(const float* __restrict__ in, unsigned short* __restrict__ out, int n4) {
  int i = blockIdx.x * 256 + threadIdx.x;
  if (i >= n4) return;
  float4 v = ((const float4*)in)[i];
  ushort4 o;
  o.x = f2bf(v.x); o.y = f2bf(v.y); o.z = f2bf(v.z); o.w = f2bf(v.w);
  ((ushort4*)out)[i] = o;
}

// ---------------- fp32 -> bf16 convert (all 4 weights, one launch) ----------------
__global__ void cvt_w_kernel(const float* __restrict__ w0, const float* __restrict__ w1,
                             const float* __restrict__ w2, const float* __restrict__ w3,
                             unsigned short* __restrict__ o0, unsigned short* __restrict__ o1,
                             unsigned short* __restrict__ o2, unsigned short* __restrict__ o3) {
  int idx = blockIdx.x * 256 + threadIdx.x;     // [0, 4*262144)
  int w = idx >> 18, i = idx & 262143;
  const float* src = (w == 0) ? w0 : (w == 1) ? w1 : (w == 2) ? w2 : w3;
  unsigned short* dst = (w == 0) ? o0 : (w == 1) ? o1 : (w == 2) ? o2 : o3;
  float4 v = ((const float4*)src)[i];
  ushort4 o;
  o.x = f2bf(v.x); o.y = f2bf(v.y); o.z = f2bf(v.z); o.w = f2bf(v.w);
  ((ushort4*)dst)[i] = o;
}

// ---------------- Fused QKV GEMM: A[8192,1024] * Wqkv[3072,1024]^T ----------------
// Q/K -> (B,H,S,DK) bf16 ; V -> (B,H,DK,S) bf16
__global__ __launch_bounds__(256) void gemm_qkv(const unsigned short* __restrict__ A,
                                                const unsigned short* __restrict__ W,
                                                unsigned short* __restrict__ Qo,
                                                unsigned short* __restrict__ Ko,
                                                unsigned short* __restrict__ Vo) {
  const int K = 1024;
  int bn = blockIdx.x;       // 0..23
  int bm = blockIdx.y;       // 0..63
  __shared__ __align__(16) char lA[128*128];
  __shared__ __align__(16) char lB[128*128];
  int t = threadIdx.x;
  int wave = t >> 6, lane = t & 63;
  int ln15 = lane & 15, lgrp = lane >> 4;
  int wr = wave >> 1, wc = wave & 1;

  f32x4 acc[4][4];
#pragma unroll
  for (int m = 0; m < 4; ++m)
#pragma unroll
    for (int n = 0; n < 4; ++n) { f32x4 z = {0.f,0.f,0.f,0.f}; acc[m][n] = z; }

  const char* Ab = (const char*)A + (size_t)bm * 128 * (K*2);
  const char* Bb = (const char*)W + (size_t)bn * 128 * (K*2);

  for (int k0 = 0; k0 < K; k0 += 64) {
#pragma unroll
    for (int i = 0; i < 4; ++i) {
      int ch = i*256 + t;
      int a = ch << 4;
      int r = a >> 7;
      int cb = (a & 127) ^ ((r & 7) << 4);
      GLDS16(Ab + (size_t)r*(K*2) + k0*2 + cb, lA + a);
      GLDS16(Bb + (size_t)r*(K*2) + k0*2 + cb, lB + a);
    }
    __syncthreads();
#pragma unroll
    for (int kf = 0; kf < 2; ++kf) {
      int cb = kf*64 + lgrp*16;
      short8 af[4], bfr[4];
#pragma unroll
      for (int m = 0; m < 4; ++m) {
        int r = wr*64 + m*16 + ln15;
        af[m] = *(const short8*)(lA + r*128 + (cb ^ ((r & 7) << 4)));
      }
#pragma unroll
      for (int n = 0; n < 4; ++n) {
        int r = wc*64 + n*16 + ln15;
        bfr[n] = *(const short8*)(lB + r*128 + (cb ^ ((r & 7) << 4)));
      }
#pragma unroll
      for (int m = 0; m < 4; ++m)
#pragma unroll
        for (int n = 0; n < 4; ++n)
          acc[m][n] = __builtin_amdgcn_mfma_f32_16x16x32_bf16(af[m], bfr[n], acc[m][n], 0, 0, 0);
    }
    __syncthreads();
  }

  int proj = bn >> 3;          // 0=Q 1=K 2=V (uniform per block)
#pragma unroll
  for (int m = 0; m < 4; ++m)
#pragma unroll
    for (int n = 0; n < 4; ++n)
#pragma unroll
      for (int r = 0; r < 4; ++r) {
        int row = bm*128 + wr*64 + m*16 + lgrp*4 + r;
        int cc = (bn & 7)*128 + wc*64 + n*16 + ln15;
        int b = row >> 11, s = row & (S_-1);
        int h = cc >> 6, dk = cc & 63;
        unsigned short v = f2bf(acc[m][n][r]);
        if (proj == 0)      Qo[(((size_t)(b*H_ + h)*S_ + s) << 6) + dk] = v;
        else if (proj == 1) Ko[(((size_t)(b*H_ + h)*S_ + s) << 6) + dk] = v;
        else                Vo[(((size_t)(b*H_ + h)*DK_ + dk) * S_) + s] = v;
      }
}

// ---------------- Final GEMM: C[M,N] fp32 = A[M,K]bf16 * W[N,K]^T ----------------
__global__ __launch_bounds__(256) void gemm_out(const unsigned short* __restrict__ A,
                                                const unsigned short* __restrict__ W,
                                                float* __restrict__ Out) {
  const int K = 1024, N = 1024;
  int bx = blockIdx.x;
  int bm = bx >> 3, bn = bx & 7;
  __shared__ __align__(16) char lA[128*128];
  __shared__ __align__(16) char lB[128*128];
  int t = threadIdx.x;
  int wave = t >> 6, lane = t & 63;
  int ln15 = lane & 15, lgrp = lane >> 4;
  int wr = wave >> 1, wc = wave & 1;

  f32x4 acc[4][4];
#pragma unroll
  for (int m = 0; m < 4; ++m)
#pragma unroll
    for (int n = 0; n < 4; ++n) { f32x4 z = {0.f,0.f,0.f,0.f}; acc[m][n] = z; }

  const char* Ab = (const char*)A + (size_t)bm * 128 * (K*2);
  const char* Bb = (const char*)W + (size_t)bn * 128 * (K*2);

  for (int k0 = 0; k0 < K; k0 += 64) {
#pragma unroll
    for (int i = 0; i < 4; ++i) {
      int ch = i*256 + t;
      int a = ch << 4;
      int r = a >> 7;
      int cb = (a & 127) ^ ((r & 7) << 4);
      GLDS16(Ab + (size_t)r*(K*2) + k0*2 + cb, lA + a);
      GLDS16(Bb + (size_t)r*(K*2) + k0*2 + cb, lB + a);
    }
    __syncthreads();
#pragma unroll
    for (int kf = 0; kf < 2; ++kf) {
      int cb = kf*64 + lgrp*16;
      short8 af[4], bfr[4];
#pragma unroll
      for (int m = 0; m < 4; ++m) {
        int r = wr*64 + m*16 + ln15;
        af[m] = *(const short8*)(lA + r*128 + (cb ^ ((r & 7) << 4)));
      }
#pragma unroll
      for (int n = 0; n < 4; ++n) {
        int r = wc*64 + n*16 + ln15;
        bfr[n] = *(const short8*)(lB + r*128 + (cb ^ ((r & 7) << 4)));
      }
#pragma unroll
      for (int m = 0; m < 4; ++m)
#pragma unroll
        for (int n = 0; n < 4; ++n)
          acc[m][n] = __builtin_amdgcn_mfma_f32_16x16x32_bf16(af[m], bfr[n], acc[m][n], 0, 0, 0);
    }
    __syncthreads();
  }

#pragma unroll
  for (int m = 0; m < 4; ++m)
#pragma unroll
    for (int n = 0; n < 4; ++n)
#pragma unroll
      for (int r = 0; r < 4; ++r) {
        int row = bm*128 + wr*64 + m*16 + lgrp*4 + r;
        int col = bn*128 + wc*64 + n*16 + ln15;
        Out[(size_t)row * N + col] = acc[m][n][r];
      }
}

// ---------------- RoPE on Q (scaled 1/8) and K, one launch, 16B/thread ----------------
__global__ void rope_kernel(unsigned short* __restrict__ Qb, unsigned short* __restrict__ Kb,
                            const int* __restrict__ pos) {
  int idx = blockIdx.x * 256 + threadIdx.x;     // [0, 2^21)
  int g = idx & 1048575;
  unsigned short* base = (idx >> 20) ? Kb : Qb;
  float scale = (idx >> 20) ? 1.0f : 0.125f;
  int jb = g & 7;                 // 8-bf16 group within the 64-dk row
  int s = (g >> 3) & (S_-1);
  int bh = g >> 14;
  unsigned short* p = base + (((size_t)bh * S_ + s) << 6) + jb*8;
  short8 v = *(short8*)p;
  float ps = (float)pos[s];
#pragma unroll
  for (int jj = 0; jj < 4; ++jj) {
    int j = jb*4 + jj;
    float freq = exp2f(-(float)j * (13.287712379549449f / 32.0f));
    float ang = ps * freq;
    float sn, cs;
    sincosf(ang, &sn, &cs);
    float x1 = bf2f((unsigned short)v[2*jj]), x2 = bf2f((unsigned short)v[2*jj+1]);
    v[2*jj]   = (short)f2bf((x1*cs - x2*sn) * scale);
    v[2*jj+1] = (short)f2bf((x1*sn + x2*cs) * scale);
  }
  *(short8*)p = v;
}

// ---------------- Flash attention, swapped 32x32, causal-fold paired strips ----------
// Block = strips qtA=p (light) and qtB=15-p (heavy), same head: uniform 34 tiles/block.
// Strip A's kv range is a prefix of strip B's -> shared K/V staging, dual-ILP tiles.
__global__ __launch_bounds__(256) void attn_kernel(const unsigned short* __restrict__ Q,
                                                   const unsigned short* __restrict__ Kg,
                                                   const unsigned short* __restrict__ VT,
                                                   unsigned short* __restrict__ O) {
  const float L2E = 1.4426950408889634f;
  int bid = blockIdx.x;
  int bh = bid & 63;
  int p = bid >> 6;                  // 0..7
  int qtA = p, qtB = 15 - p;
  int b = bh >> 4, h = bh & 15;
  const int qbA = qtA * 128, qbB = qtB * 128;
  const unsigned short* QpA = Q + (((size_t)bh * S_ + qbA) << 6);
  const unsigned short* QpB = Q + (((size_t)bh * S_ + qbB) << 6);
  const char* Kp = (const char*)(Kg + ((size_t)bh * S_ << 6));
  const char* Vp = (const char*)(VT + (size_t)bh * DK_ * S_);

  __shared__ __align__(16) char lK[2][64*128];
  __shared__ __align__(16) char lV[2][64*128];

  int t = threadIdx.x, wave = t >> 6, lane = t & 63;
  int ln31 = lane & 31, hi = lane >> 5;
  int qw = wave * 32;

  short8 qfA[4], qfB[4];
#pragma unroll
  for (int kk = 0; kk < 4; ++kk) {
    qfA[kk] = *(const short8*)(QpA + (size_t)(qw + ln31)*64 + kk*16 + hi*8);
    qfB[kk] = *(const short8*)(QpB + (size_t)(qw + ln31)*64 + kk*16 + hi*8);
  }

  f32x16 ocA[2], ocB[2];
#pragma unroll
  for (int dh = 0; dh < 2; ++dh)
#pragma unroll
    for (int r = 0; r < 16; ++r) { ocA[dh][r] = 0.f; ocB[dh][r] = 0.f; }
  float miA = -__builtin_inff(), liA = 0.f;
  float miB = -__builtin_inff(), liB = 0.f;

  const int ntA = 2*qtA + 2, ntB = 2*qtB + 2;    // ntA < ntB always (p<8)

#define STAGE_KV(bufi, ktv) do { \
    _Pragma("unroll") \
    for (int i_ = 0; i_ < 2; ++i_) { \
      int ch_ = i_*256 + t; \
      int a_ = ch_ << 4; \
      int r_ = a_ >> 7; \
      int cb_ = (a_ & 127) ^ ((r_ & 7) << 4); \
      GLDS16(Kp + (size_t)((ktv)*64 + r_)*128 + cb_, lK[bufi] + a_); \
      GLDS16(Vp + (size_t)r_*(S_*2) + (size_t)(ktv)*128 + cb_, lV[bufi] + a_); \
    } \
  } while (0)

#define COMPUTE_STRIP(QF, OC, MI, LI, QB) do { \
    f32x16 sc_[2]; \
    __builtin_amdgcn_s_setprio(1); \
    _Pragma("unroll") \
    for (int t2 = 0; t2 < 2; ++t2) { \
      f32x16 a_; \
      _Pragma("unroll") \
      for (int r = 0; r < 16; ++r) a_[r] = 0.f; \
      int rK_ = t2*32 + ln31; \
      int swzK_ = (rK_ & 7) << 4; \
      _Pragma("unroll") \
      for (int kk = 0; kk < 4; ++kk) { \
        short8 kfr_ = *(const short8*)(cK + rK_*128 + ((kk*32 + hi*16) ^ swzK_)); \
        a_ = __builtin_amdgcn_mfma_f32_32x32x16_bf16(kfr_, QF[kk], a_, 0, 0, 0); \
      } \
      sc_[t2] = a_; \
    } \
    __builtin_amdgcn_s_setprio(0); \
    if (kt*64 + 63 > (QB) + qw) { \
      _Pragma("unroll") \
      for (int t2 = 0; t2 < 2; ++t2) \
        _Pragma("unroll") \
        for (int r = 0; r < 16; ++r) { \
          int kv_ = kt*64 + t2*32 + (r & 3) + 8*(r >> 2) + 4*hi; \
          if (kv_ > (QB) + qw + ln31) sc_[t2][r] = -__builtin_inff(); \
        } \
    } \
    float mxa_ = fmaxf(sc_[0][0], sc_[0][1]); \
    float mxb_ = fmaxf(sc_[1][0], sc_[1][1]); \
    _Pragma("unroll") \
    for (int r = 2; r < 16; r += 2) { \
      mxa_ = fmaxf(fmaxf(sc_[0][r], sc_[0][r+1]), mxa_); \
      mxb_ = fmaxf(fmaxf(sc_[1][r], sc_[1][r+1]), mxb_); \
    } \
    float mx_ = fmaxf(mxa_, mxb_); \
    mx_ = fmaxf(mx_, __shfl_xor(mx_, 32)); \
    if (!__all(mx_ - (MI) <= 8.f)) { \
      float mn_ = fmaxf((MI), mx_); \
      float corr_ = exp2f(((MI) - mn_) * L2E); \
      (LI) *= corr_; \
      _Pragma("unroll") \
      for (int dh = 0; dh < 2; ++dh) \
        _Pragma("unroll") \
        for (int r = 0; r < 16; ++r) OC[dh][r] *= corr_; \
      (MI) = mn_; \
    } \
    float ls_ = 0.f; \
    _Pragma("unroll") \
    for (int t2 = 0; t2 < 2; ++t2) \
      _Pragma("unroll") \
      for (int r = 0; r < 16; ++r) { \
        float pv_ = exp2f((sc_[t2][r] - (MI)) * L2E); \
        sc_[t2][r] = pv_; ls_ += pv_; \
      } \
    (LI) += ls_; \
    _Pragma("unroll") \
    for (int kk = 0; kk < 4; ++kk) { \
      int base_ = 8*(kk & 1), tt_ = kk >> 1; \
      unsigned P0_ = cvtpk_bf16(sc_[tt_][base_+0], sc_[tt_][base_+1]); \
      unsigned P1_ = cvtpk_bf16(sc_[tt_][base_+2], sc_[tt_][base_+3]); \
      unsigned Q0_ = cvtpk_bf16(sc_[tt_][base_+4], sc_[tt_][base_+5]); \
      unsigned Q1_ = cvtpk_bf16(sc_[tt_][base_+6], sc_[tt_][base_+7]); \
      u32x2 r01_ = __builtin_amdgcn_permlane32_swap(P0_, Q0_, false, false); \
      u32x2 s01_ = __builtin_amdgcn_permlane32_swap(P1_, Q1_, false, false); \
      union { unsigned u[4]; short8 s8; } pf_; \
      pf_.u[0] = r01_[0]; pf_.u[1] = s01_[0]; pf_.u[2] = r01_[1]; pf_.u[3] = s01_[1]; \
      __builtin_amdgcn_s_setprio(1); \
      _Pragma("unroll") \
      for (int dh = 0; dh < 2; ++dh) { \
        int rV_ = dh*32 + ln31; \
        short8 vfr_ = *(const short8*)(cV + rV_*128 + ((kk*32 + hi*16) ^ ((rV_ & 7) << 4))); \
        OC[dh] = __builtin_amdgcn_mfma_f32_32x32x16_bf16(vfr_, pf_.s8, OC[dh], 0, 0, 0); \
      } \
      __builtin_amdgcn_s_setprio(0); \
    } \
  } while (0)

#define STORE_STRIP(OC, LI, QB) do { \
    float lf_ = (LI) + __shfl_xor((LI), 32); \
    float ri_ = 1.0f / lf_; \
    int qg_ = (QB) + qw + ln31; \
    _Pragma("unroll") \
    for (int dh = 0; dh < 2; ++dh) \
      _Pragma("unroll") \
      for (int rg = 0; rg < 4; ++rg) { \
        ushort4 pk4_; \
        pk4_.x = f2bf(OC[dh][rg*4+0] * ri_); \
        pk4_.y = f2bf(OC[dh][rg*4+1] * ri_); \
        pk4_.z = f2bf(OC[dh][rg*4+2] * ri_); \
        pk4_.w = f2bf(OC[dh][rg*4+3] * ri_); \
        int dk_ = dh*32 + 8*rg + 4*hi; \
        *(ushort4*)(O + (((size_t)(b*S_ + qg_)) << 10) + h*64 + dk_) = pk4_; \
      } \
  } while (0)

  STAGE_KV(0, 0);
  __syncthreads();

  int cur = 0;
  for (int kt = 0; kt < ntB; ++kt) {
    if (kt + 1 < ntB) STAGE_KV(cur ^ 1, kt + 1);

    const char* cK = lK[cur];
    const char* cV = lV[cur];

    if (kt*64 <= qbB + qw + 31)
      COMPUTE_STRIP(qfB, ocB, miB, liB, qbB);
    if (kt < ntA && kt*64 <= qbA + qw + 31)
      COMPUTE_STRIP(qfA, ocA, miA, liA, qbA);

    __syncthreads();
    cur ^= 1;
  }
#undef STAGE_KV
#undef COMPUTE_STRIP

  STORE_STRIP(ocB, liB, qbB);
  STORE_STRIP(ocA, liA, qbA);
#undef STORE_STRIP
}

extern "C" void kernel_launch(void* const* d_in, const int* in_sizes, int n_in,
                              void* d_out, int out_size, void* d_ws, size_t ws_size,
                              hipStream_t stream) {
  const float* x  = (const float*)d_in[0];
  const float* Wq = (const float*)d_in[1];
  const float* Wk = (const float*)d_in[2];
  const float* Wv = (const float*)d_in[3];
  const float* Wo = (const float*)d_in[4];
  const int* pos  = (const int*)d_in[5];

  char* ws = (char*)d_ws;
  unsigned short* xb  = (unsigned short*)(ws + 0);          // 16 MB, also reused as O
  unsigned short* wqb = (unsigned short*)(ws + 16777216);   // [3072,1024] contiguous qkv
  unsigned short* wkb = (unsigned short*)(ws + 18874368);
  unsigned short* wvb = (unsigned short*)(ws + 20971520);
  unsigned short* wob = (unsigned short*)(ws + 23068672);
  unsigned short* Qb  = (unsigned short*)(ws + 25165824);   // 16 MB
  unsigned short* Kb  = (unsigned short*)(ws + 41943040);   // 16 MB
  unsigned short* VTb = (unsigned short*)(ws + 58720256);   // 16 MB
  unsigned short* Ob  = xb;  // alias: xb dead after QKV projection (stream-ordered)

  cvt_kernel<<<8192, 256, 0, stream>>>(x, xb, 2097152);
  cvt_w_kernel<<<4096, 256, 0, stream>>>(Wq, Wk, Wv, Wo, wqb, wkb, wvb, wob);

  gemm_qkv<<<dim3(24, 64), 256, 0, stream>>>(xb, wqb, Qb, Kb, VTb);

  rope_kernel<<<8192, 256, 0, stream>>>(Qb, Kb, pos);   // Q scaled 1/8 inside

  attn_kernel<<<512, 256, 0, stream>>>(Qb, Kb, VTb, Ob);

  gemm_out<<<512, 256, 0, stream>>>(Ob, wob, (float*)d_out);
}

// Round 5
// 223.603 us; speedup vs baseline: 1.0457x; 1.0457x over previous
//
#include <hip/hip_runtime.h>
#include <stdint.h>

#define B_ 4
#define S_ 2048
#define D_ 1024
#define H_ 16
#define DK_ 64
#define M_ (B_*S_)   // 8192

typedef __attribute__((ext_vector_type(8))) short short8;
typedef __attribute__((ext_vector_type(4))) float f32x4;
typedef __attribute__((ext_vector_type(16))) float f32x16;
typedef __attribute__((ext_vector_type(2))) unsigned int u32x2;

static __device__ __forceinline__ float bf2f(unsigned short s) {
  union { unsigned u; float f; } v; v.u = ((unsigned)s) << 16; return v.f;
}
static __device__ __forceinline__ unsigned short f2bf(float f) {
  union { float f; unsigned u; } v; v.f = f;
  unsigned r = v.u + 0x7fffu + ((v.u >> 16) & 1u);
  return (unsigned short)(r >> 16);
}
static __device__ __forceinline__ unsigned cvtpk_bf16(float lo, float hi) {
  unsigned r;
  asm("v_cvt_pk_bf16_f32 %0, %1, %2" : "=v"(r) : "v"(lo), "v"(hi));
  return r;
}

#define GLDS16(g, l) __builtin_amdgcn_global_load_lds( \
    (const __attribute__((address_space(1))) unsigned int*)(g), \
    (__attribute__((address_space(3))) unsigned int*)(l), 16, 0, 0)

// ---------------- fp32 -> bf16 convert (x) ----------------
__global__ void cvt_kernel(const float* __restrict__ in, unsigned short* __restrict__ out, int n4) {
  int i = blockIdx.x * 256 + threadIdx.x;
  if (i >= n4) return;
  float4 v = ((const float4*)in)[i];
  ushort4 o;
  o.x = f2bf(v.x); o.y = f2bf(v.y); o.z = f2bf(v.z); o.w = f2bf(v.w);
  ((ushort4*)out)[i] = o;
}

// ---------------- fp32 -> bf16 convert (all 4 weights, one launch) ----------------
__global__ void cvt_w_kernel(const float* __restrict__ w0, const float* __restrict__ w1,
                             const float* __restrict__ w2, const float* __restrict__ w3,
                             unsigned short* __restrict__ o0, unsigned short* __restrict__ o1,
                             unsigned short* __restrict__ o2, unsigned short* __restrict__ o3) {
  int idx = blockIdx.x * 256 + threadIdx.x;     // [0, 4*262144)
  int w = idx >> 18, i = idx & 262143;
  const float* src = (w == 0) ? w0 : (w == 1) ? w1 : (w == 2) ? w2 : w3;
  unsigned short* dst = (w == 0) ? o0 : (w == 1) ? o1 : (w == 2) ? o2 : o3;
  float4 v = ((const float4*)src)[i];
  ushort4 o;
  o.x = f2bf(v.x); o.y = f2bf(v.y); o.z = f2bf(v.z); o.w = f2bf(v.w);
  ((ushort4*)dst)[i] = o;
}

// ---- shared GEMM staging macro: stage 128x64 bf16 tiles of A and B (dbuf) ----
#define GSTAGE(bufi, k0v) do { \
    _Pragma("unroll") \
    for (int i_ = 0; i_ < 4; ++i_) { \
      int a_ = (i_*256 + t) << 4; \
      int r_ = a_ >> 7; \
      int cb_ = (a_ & 127) ^ ((r_ & 7) << 4); \
      GLDS16(Ab + (size_t)r_*(K*2) + (size_t)(k0v)*2 + cb_, lA[bufi] + a_); \
      GLDS16(Bb + (size_t)r_*(K*2) + (size_t)(k0v)*2 + cb_, lB[bufi] + a_); \
    } \
  } while (0)

#define GEMM_COMPUTE(bufi) do { \
    const char* cA_ = lA[bufi]; \
    const char* cB_ = lB[bufi]; \
    _Pragma("unroll") \
    for (int kf = 0; kf < 2; ++kf) { \
      int cb = kf*64 + lgrp*16; \
      short8 af[4], bfr[4]; \
      _Pragma("unroll") \
      for (int m = 0; m < 4; ++m) { \
        int r = wr*64 + m*16 + ln15; \
        af[m] = *(const short8*)(cA_ + r*128 + (cb ^ ((r & 7) << 4))); \
      } \
      _Pragma("unroll") \
      for (int n = 0; n < 4; ++n) { \
        int r = wc*64 + n*16 + ln15; \
        bfr[n] = *(const short8*)(cB_ + r*128 + (cb ^ ((r & 7) << 4))); \
      } \
      __builtin_amdgcn_s_setprio(1); \
      _Pragma("unroll") \
      for (int m = 0; m < 4; ++m) \
        _Pragma("unroll") \
        for (int n = 0; n < 4; ++n) \
          acc[m][n] = __builtin_amdgcn_mfma_f32_16x16x32_bf16(af[m], bfr[n], acc[m][n], 0, 0, 0); \
      __builtin_amdgcn_s_setprio(0); \
    } \
  } while (0)

// ---------------- Fused QKV GEMM (2-phase dbuf): A[8192,1024] * Wqkv[3072,1024]^T ----
// Q/K -> (B,H,S,DK) bf16 ; V -> (B,H,DK,S) bf16
__global__ __launch_bounds__(256) void gemm_qkv(const unsigned short* __restrict__ A,
                                                const unsigned short* __restrict__ W,
                                                unsigned short* __restrict__ Qo,
                                                unsigned short* __restrict__ Ko,
                                                unsigned short* __restrict__ Vo) {
  const int K = 1024;
  int bn = blockIdx.x;       // 0..23
  int bm = blockIdx.y;       // 0..63
  __shared__ __align__(16) char lA[2][128*128];
  __shared__ __align__(16) char lB[2][128*128];
  int t = threadIdx.x;
  int wave = t >> 6, lane = t & 63;
  int ln15 = lane & 15, lgrp = lane >> 4;
  int wr = wave >> 1, wc = wave & 1;

  f32x4 acc[4][4];
#pragma unroll
  for (int m = 0; m < 4; ++m)
#pragma unroll
    for (int n = 0; n < 4; ++n) { f32x4 z = {0.f,0.f,0.f,0.f}; acc[m][n] = z; }

  const char* Ab = (const char*)A + (size_t)bm * 128 * (K*2);
  const char* Bb = (const char*)W + (size_t)bn * 128 * (K*2);

  GSTAGE(0, 0);
  __syncthreads();
  int cur = 0;
  for (int k0 = 0; k0 < K; k0 += 64) {
    if (k0 + 64 < K) GSTAGE(cur ^ 1, k0 + 64);   // prefetch next tile (overlaps compute)
    GEMM_COMPUTE(cur);
    __syncthreads();                              // drains prefetch vmcnt + joins
    cur ^= 1;
  }

  int proj = bn >> 3;          // 0=Q 1=K 2=V (uniform per block)
#pragma unroll
  for (int m = 0; m < 4; ++m)
#pragma unroll
    for (int n = 0; n < 4; ++n)
#pragma unroll
      for (int r = 0; r < 4; ++r) {
        int row = bm*128 + wr*64 + m*16 + lgrp*4 + r;
        int cc = (bn & 7)*128 + wc*64 + n*16 + ln15;
        int b = row >> 11, s = row & (S_-1);
        int h = cc >> 6, dk = cc & 63;
        unsigned short v = f2bf(acc[m][n][r]);
        if (proj == 0)      Qo[(((size_t)(b*H_ + h)*S_ + s) << 6) + dk] = v;
        else if (proj == 1) Ko[(((size_t)(b*H_ + h)*S_ + s) << 6) + dk] = v;
        else                Vo[(((size_t)(b*H_ + h)*DK_ + dk) * S_) + s] = v;
      }
}

// ---------------- Final GEMM (2-phase dbuf): C[M,N] fp32 = A[M,K]bf16 * W[N,K]^T ----
__global__ __launch_bounds__(256) void gemm_out(const unsigned short* __restrict__ A,
                                                const unsigned short* __restrict__ W,
                                                float* __restrict__ Out) {
  const int K = 1024, N = 1024;
  int bx = blockIdx.x;
  int bm = bx >> 3, bn = bx & 7;
  __shared__ __align__(16) char lA[2][128*128];
  __shared__ __align__(16) char lB[2][128*128];
  int t = threadIdx.x;
  int wave = t >> 6, lane = t & 63;
  int ln15 = lane & 15, lgrp = lane >> 4;
  int wr = wave >> 1, wc = wave & 1;

  f32x4 acc[4][4];
#pragma unroll
  for (int m = 0; m < 4; ++m)
#pragma unroll
    for (int n = 0; n < 4; ++n) { f32x4 z = {0.f,0.f,0.f,0.f}; acc[m][n] = z; }

  const char* Ab = (const char*)A + (size_t)bm * 128 * (K*2);
  const char* Bb = (const char*)W + (size_t)bn * 128 * (K*2);

  GSTAGE(0, 0);
  __syncthreads();
  int cur = 0;
  for (int k0 = 0; k0 < K; k0 += 64) {
    if (k0 + 64 < K) GSTAGE(cur ^ 1, k0 + 64);
    GEMM_COMPUTE(cur);
    __syncthreads();
    cur ^= 1;
  }

#pragma unroll
  for (int m = 0; m < 4; ++m)
#pragma unroll
    for (int n = 0; n < 4; ++n)
#pragma unroll
      for (int r = 0; r < 4; ++r) {
        int row = bm*128 + wr*64 + m*16 + lgrp*4 + r;
        int col = bn*128 + wc*64 + n*16 + ln15;
        Out[(size_t)row * N + col] = acc[m][n][r];
      }
}

// ---------------- RoPE on Q (scaled 1/8) and K, one launch, 16B/thread ----------------
__global__ void rope_kernel(unsigned short* __restrict__ Qb, unsigned short* __restrict__ Kb,
                            const int* __restrict__ pos) {
  int idx = blockIdx.x * 256 + threadIdx.x;     // [0, 2^21)
  int g = idx & 1048575;
  unsigned short* base = (idx >> 20) ? Kb : Qb;
  float scale = (idx >> 20) ? 1.0f : 0.125f;
  int jb = g & 7;                 // 8-bf16 group within the 64-dk row
  int s = (g >> 3) & (S_-1);
  int bh = g >> 14;
  unsigned short* p = base + (((size_t)bh * S_ + s) << 6) + jb*8;
  short8 v = *(short8*)p;
  float ps = (float)pos[s];
#pragma unroll
  for (int jj = 0; jj < 4; ++jj) {
    int j = jb*4 + jj;
    float freq = exp2f(-(float)j * (13.287712379549449f / 32.0f));
    float ang = ps * freq;
    float sn, cs;
    sincosf(ang, &sn, &cs);
    float x1 = bf2f((unsigned short)v[2*jj]), x2 = bf2f((unsigned short)v[2*jj+1]);
    v[2*jj]   = (short)f2bf((x1*cs - x2*sn) * scale);
    v[2*jj+1] = (short)f2bf((x1*sn + x2*cs) * scale);
  }
  *(short8*)p = v;
}

// ---------------- Flash attention, swapped 32x32, causal-fold paired strips ----------
// Block = strips qtA=p (light) and qtB=15-p (heavy), same head: uniform 34 tiles/block.
// Strip A's kv range is a prefix of strip B's -> shared K/V staging, dual-ILP tiles.
__global__ __launch_bounds__(256) void attn_kernel(const unsigned short* __restrict__ Q,
                                                   const unsigned short* __restrict__ Kg,
                                                   const unsigned short* __restrict__ VT,
                                                   unsigned short* __restrict__ O) {
  const float L2E = 1.4426950408889634f;
  int bid = blockIdx.x;
  int bh = bid & 63;
  int p = bid >> 6;                  // 0..7
  int qtA = p, qtB = 15 - p;
  int b = bh >> 4, h = bh & 15;
  const int qbA = qtA * 128, qbB = qtB * 128;
  const unsigned short* QpA = Q + (((size_t)bh * S_ + qbA) << 6);
  const unsigned short* QpB = Q + (((size_t)bh * S_ + qbB) << 6);
  const char* Kp = (const char*)(Kg + ((size_t)bh * S_ << 6));
  const char* Vp = (const char*)(VT + (size_t)bh * DK_ * S_);

  __shared__ __align__(16) char lK[2][64*128];
  __shared__ __align__(16) char lV[2][64*128];

  int t = threadIdx.x, wave = t >> 6, lane = t & 63;
  int ln31 = lane & 31, hi = lane >> 5;
  int qw = wave * 32;

  short8 qfA[4], qfB[4];
#pragma unroll
  for (int kk = 0; kk < 4; ++kk) {
    qfA[kk] = *(const short8*)(QpA + (size_t)(qw + ln31)*64 + kk*16 + hi*8);
    qfB[kk] = *(const short8*)(QpB + (size_t)(qw + ln31)*64 + kk*16 + hi*8);
  }

  f32x16 ocA[2], ocB[2];
#pragma unroll
  for (int dh = 0; dh < 2; ++dh)
#pragma unroll
    for (int r = 0; r < 16; ++r) { ocA[dh][r] = 0.f; ocB[dh][r] = 0.f; }
  float miA = -__builtin_inff(), liA = 0.f;
  float miB = -__builtin_inff(), liB = 0.f;

  const int ntA = 2*qtA + 2, ntB = 2*qtB + 2;    // ntA < ntB always (p<8)

#define STAGE_KV(bufi, ktv) do { \
    _Pragma("unroll") \
    for (int i_ = 0; i_ < 2; ++i_) { \
      int ch_ = i_*256 + t; \
      int a_ = ch_ << 4; \
      int r_ = a_ >> 7; \
      int cb_ = (a_ & 127) ^ ((r_ & 7) << 4); \
      GLDS16(Kp + (size_t)((ktv)*64 + r_)*128 + cb_, lK[bufi] + a_); \
      GLDS16(Vp + (size_t)r_*(S_*2) + (size_t)(ktv)*128 + cb_, lV[bufi] + a_); \
    } \
  } while (0)

#define COMPUTE_STRIP(QF, OC, MI, LI, QB) do { \
    f32x16 sc_[2]; \
    __builtin_amdgcn_s_setprio(1); \
    _Pragma("unroll") \
    for (int t2 = 0; t2 < 2; ++t2) { \
      f32x16 a_; \
      _Pragma("unroll") \
      for (int r = 0; r < 16; ++r) a_[r] = 0.f; \
      int rK_ = t2*32 + ln31; \
      int swzK_ = (rK_ & 7) << 4; \
      _Pragma("unroll") \
      for (int kk = 0; kk < 4; ++kk) { \
        short8 kfr_ = *(const short8*)(cK + rK_*128 + ((kk*32 + hi*16) ^ swzK_)); \
        a_ = __builtin_amdgcn_mfma_f32_32x32x16_bf16(kfr_, QF[kk], a_, 0, 0, 0); \
      } \
      sc_[t2] = a_; \
    } \
    __builtin_amdgcn_s_setprio(0); \
    if (kt*64 + 63 > (QB) + qw) { \
      _Pragma("unroll") \
      for (int t2 = 0; t2 < 2; ++t2) \
        _Pragma("unroll") \
        for (int r = 0; r < 16; ++r) { \
          int kv_ = kt*64 + t2*32 + (r & 3) + 8*(r >> 2) + 4*hi; \
          if (kv_ > (QB) + qw + ln31) sc_[t2][r] = -__builtin_inff(); \
        } \
    } \
    float mxa_ = fmaxf(sc_[0][0], sc_[0][1]); \
    float mxb_ = fmaxf(sc_[1][0], sc_[1][1]); \
    _Pragma("unroll") \
    for (int r = 2; r < 16; r += 2) { \
      mxa_ = fmaxf(fmaxf(sc_[0][r], sc_[0][r+1]), mxa_); \
      mxb_ = fmaxf(fmaxf(sc_[1][r], sc_[1][r+1]), mxb_); \
    } \
    float mx_ = fmaxf(mxa_, mxb_); \
    mx_ = fmaxf(mx_, __shfl_xor(mx_, 32)); \
    if (!__all(mx_ - (MI) <= 8.f)) { \
      float mn_ = fmaxf((MI), mx_); \
      float corr_ = exp2f(((MI) - mn_) * L2E); \
      (LI) *= corr_; \
      _Pragma("unroll") \
      for (int dh = 0; dh < 2; ++dh) \
        _Pragma("unroll") \
        for (int r = 0; r < 16; ++r) OC[dh][r] *= corr_; \
      (MI) = mn_; \
    } \
    float ls_ = 0.f; \
    _Pragma("unroll") \
    for (int t2 = 0; t2 < 2; ++t2) \
      _Pragma("unroll") \
      for (int r = 0; r < 16; ++r) { \
        float pv_ = exp2f((sc_[t2][r] - (MI)) * L2E); \
        sc_[t2][r] = pv_; ls_ += pv_; \
      } \
    (LI) += ls_; \
    _Pragma("unroll") \
    for (int kk = 0; kk < 4; ++kk) { \
      int base_ = 8*(kk & 1), tt_ = kk >> 1; \
      unsigned P0_ = cvtpk_bf16(sc_[tt_][base_+0], sc_[tt_][base_+1]); \
      unsigned P1_ = cvtpk_bf16(sc_[tt_][base_+2], sc_[tt_][base_+3]); \
      unsigned Q0_ = cvtpk_bf16(sc_[tt_][base_+4], sc_[tt_][base_+5]); \
      unsigned Q1_ = cvtpk_bf16(sc_[tt_][base_+6], sc_[tt_][base_+7]); \
      u32x2 r01_ = __builtin_amdgcn_permlane32_swap(P0_, Q0_, false, false); \
      u32x2 s01_ = __builtin_amdgcn_permlane32_swap(P1_, Q1_, false, false); \
      union { unsigned u[4]; short8 s8; } pf_; \
      pf_.u[0] = r01_[0]; pf_.u[1] = s01_[0]; pf_.u[2] = r01_[1]; pf_.u[3] = s01_[1]; \
      __builtin_amdgcn_s_setprio(1); \
      _Pragma("unroll") \
      for (int dh = 0; dh < 2; ++dh) { \
        int rV_ = dh*32 + ln31; \
        short8 vfr_ = *(const short8*)(cV + rV_*128 + ((kk*32 + hi*16) ^ ((rV_ & 7) << 4))); \
        OC[dh] = __builtin_amdgcn_mfma_f32_32x32x16_bf16(vfr_, pf_.s8, OC[dh], 0, 0, 0); \
      } \
      __builtin_amdgcn_s_setprio(0); \
    } \
  } while (0)

#define STORE_STRIP(OC, LI, QB) do { \
    float lf_ = (LI) + __shfl_xor((LI), 32); \
    float ri_ = 1.0f / lf_; \
    int qg_ = (QB) + qw + ln31; \
    _Pragma("unroll") \
    for (int dh = 0; dh < 2; ++dh) \
      _Pragma("unroll") \
      for (int rg = 0; rg < 4; ++rg) { \
        ushort4 pk4_; \
        pk4_.x = f2bf(OC[dh][rg*4+0] * ri_); \
        pk4_.y = f2bf(OC[dh][rg*4+1] * ri_); \
        pk4_.z = f2bf(OC[dh][rg*4+2] * ri_); \
        pk4_.w = f2bf(OC[dh][rg*4+3] * ri_); \
        int dk_ = dh*32 + 8*rg + 4*hi; \
        *(ushort4*)(O + (((size_t)(b*S_ + qg_)) << 10) + h*64 + dk_) = pk4_; \
      } \
  } while (0)

  STAGE_KV(0, 0);
  __syncthreads();

  int cur = 0;
  for (int kt = 0; kt < ntB; ++kt) {
    if (kt + 1 < ntB) STAGE_KV(cur ^ 1, kt + 1);

    const char* cK = lK[cur];
    const char* cV = lV[cur];

    if (kt*64 <= qbB + qw + 31)
      COMPUTE_STRIP(qfB, ocB, miB, liB, qbB);
    if (kt < ntA && kt*64 <= qbA + qw + 31)
      COMPUTE_STRIP(qfA, ocA, miA, liA, qbA);

    __syncthreads();
    cur ^= 1;
  }
#undef STAGE_KV
#undef COMPUTE_STRIP

  STORE_STRIP(ocB, liB, qbB);
  STORE_STRIP(ocA, liA, qbA);
#undef STORE_STRIP
}

extern "C" void kernel_launch(void* const* d_in, const int* in_sizes, int n_in,
                              void* d_out, int out_size, void* d_ws, size_t ws_size,
                              hipStream_t stream) {
  const float* x  = (const float*)d_in[0];
  const float* Wq = (const float*)d_in[1];
  const float* Wk = (const float*)d_in[2];
  const float* Wv = (const float*)d_in[3];
  const float* Wo = (const float*)d_in[4];
  const int* pos  = (const int*)d_in[5];

  char* ws = (char*)d_ws;
  unsigned short* xb  = (unsigned short*)(ws + 0);          // 16 MB, also reused as O
  unsigned short* wqb = (unsigned short*)(ws + 16777216);   // [3072,1024] contiguous qkv
  unsigned short* wkb = (unsigned short*)(ws + 18874368);
  unsigned short* wvb = (unsigned short*)(ws + 20971520);
  unsigned short* wob = (unsigned short*)(ws + 23068672);
  unsigned short* Qb  = (unsigned short*)(ws + 25165824);   // 16 MB
  unsigned short* Kb  = (unsigned short*)(ws + 41943040);   // 16 MB
  unsigned short* VTb = (unsigned short*)(ws + 58720256);   // 16 MB
  unsigned short* Ob  = xb;  // alias: xb dead after QKV projection (stream-ordered)

  cvt_kernel<<<8192, 256, 0, stream>>>(x, xb, 2097152);
  cvt_w_kernel<<<4096, 256, 0, stream>>>(Wq, Wk, Wv, Wo, wqb, wkb, wvb, wob);

  gemm_qkv<<<dim3(24, 64), 256, 0, stream>>>(xb, wqb, Qb, Kb, VTb);

  rope_kernel<<<8192, 256, 0, stream>>>(Qb, Kb, pos);   // Q scaled 1/8 inside

  attn_kernel<<<512, 256, 0, stream>>>(Qb, Kb, VTb, Ob);

  gemm_out<<<512, 256, 0, stream>>>(Ob, wob, (float*)d_out);
}

// Round 6
// 199.361 us; speedup vs baseline: 1.1728x; 1.1216x over previous
//
#include <hip/hip_runtime.h>
#include <stdint.h>

#define B_ 4
#define S_ 2048
#define D_ 1024
#define H_ 16
#define DK_ 64
#define M_ (B_*S_)   // 8192

typedef __attribute__((ext_vector_type(8))) short short8;
typedef __attribute__((ext_vector_type(4))) float f32x4;
typedef __attribute__((ext_vector_type(16))) float f32x16;
typedef __attribute__((ext_vector_type(2))) unsigned int u32x2;

static __device__ __forceinline__ float bf2f(unsigned short s) {
  union { unsigned u; float f; } v; v.u = ((unsigned)s) << 16; return v.f;
}
static __device__ __forceinline__ unsigned short f2bf(float f) {
  union { float f; unsigned u; } v; v.f = f;
  unsigned r = v.u + 0x7fffu + ((v.u >> 16) & 1u);
  return (unsigned short)(r >> 16);
}
static __device__ __forceinline__ unsigned cvtpk_bf16(float lo, float hi) {
  unsigned r;
  asm("v_cvt_pk_bf16_f32 %0, %1, %2" : "=v"(r) : "v"(lo), "v"(hi));
  return r;
}

#define GLDS16(g, l) __builtin_amdgcn_global_load_lds( \
    (const __attribute__((address_space(1))) unsigned int*)(g), \
    (__attribute__((address_space(3))) unsigned int*)(l), 16, 0, 0)

// ---------------- fp32 -> bf16 convert (x) ----------------
__global__ void cvt_kernel(const float* __restrict__ in, unsigned short* __restrict__ out, int n4) {
  int i = blockIdx.x * 256 + threadIdx.x;
  if (i >= n4) return;
  float4 v = ((const float4*)in)[i];
  ushort4 o;
  o.x = f2bf(v.x); o.y = f2bf(v.y); o.z = f2bf(v.z); o.w = f2bf(v.w);
  ((ushort4*)out)[i] = o;
}

// ---------------- fp32 -> bf16 convert (all 4 weights, one launch) ----------------
__global__ void cvt_w_kernel(const float* __restrict__ w0, const float* __restrict__ w1,
                             const float* __restrict__ w2, const float* __restrict__ w3,
                             unsigned short* __restrict__ o0, unsigned short* __restrict__ o1,
                             unsigned short* __restrict__ o2, unsigned short* __restrict__ o3) {
  int idx = blockIdx.x * 256 + threadIdx.x;     // [0, 4*262144)
  int w = idx >> 18, i = idx & 262143;
  const float* src = (w == 0) ? w0 : (w == 1) ? w1 : (w == 2) ? w2 : w3;
  unsigned short* dst = (w == 0) ? o0 : (w == 1) ? o1 : (w == 2) ? o2 : o3;
  float4 v = ((const float4*)src)[i];
  ushort4 o;
  o.x = f2bf(v.x); o.y = f2bf(v.y); o.z = f2bf(v.z); o.w = f2bf(v.w);
  ((ushort4*)dst)[i] = o;
}

// ---- shared GEMM staging macro: stage 128x64 bf16 tiles of A and B (dbuf) ----
#define GSTAGE(bufi, k0v) do { \
    _Pragma("unroll") \
    for (int i_ = 0; i_ < 4; ++i_) { \
      int a_ = (i_*256 + t) << 4; \
      int r_ = a_ >> 7; \
      int cb_ = (a_ & 127) ^ ((r_ & 7) << 4); \
      GLDS16(Ab + (size_t)r_*(K*2) + (size_t)(k0v)*2 + cb_, lA[bufi] + a_); \
      GLDS16(Bb + (size_t)r_*(K*2) + (size_t)(k0v)*2 + cb_, lB[bufi] + a_); \
    } \
  } while (0)

#define GEMM_COMPUTE(bufi) do { \
    const char* cA_ = lA[bufi]; \
    const char* cB_ = lB[bufi]; \
    _Pragma("unroll") \
    for (int kf = 0; kf < 2; ++kf) { \
      int cb = kf*64 + lgrp*16; \
      short8 af[4], bfr[4]; \
      _Pragma("unroll") \
      for (int m = 0; m < 4; ++m) { \
        int r = wr*64 + m*16 + ln15; \
        af[m] = *(const short8*)(cA_ + r*128 + (cb ^ ((r & 7) << 4))); \
      } \
      _Pragma("unroll") \
      for (int n = 0; n < 4; ++n) { \
        int r = wc*64 + n*16 + ln15; \
        bfr[n] = *(const short8*)(cB_ + r*128 + (cb ^ ((r & 7) << 4))); \
      } \
      __builtin_amdgcn_s_setprio(1); \
      _Pragma("unroll") \
      for (int m = 0; m < 4; ++m) \
        _Pragma("unroll") \
        for (int n = 0; n < 4; ++n) \
          acc[m][n] = __builtin_amdgcn_mfma_f32_16x16x32_bf16(af[m], bfr[n], acc[m][n], 0, 0, 0); \
      __builtin_amdgcn_s_setprio(0); \
    } \
  } while (0)

#define GEMM_PROLOG \
  __shared__ __align__(16) char lA[2][128*128]; \
  __shared__ __align__(16) char lB[2][128*128]; \
  int t = threadIdx.x; \
  int wave = t >> 6, lane = t & 63; \
  int ln15 = lane & 15, lgrp = lane >> 4; \
  int wr = wave >> 1, wc = wave & 1; \
  f32x4 acc[4][4]; \
  _Pragma("unroll") \
  for (int m = 0; m < 4; ++m) \
    _Pragma("unroll") \
    for (int n = 0; n < 4; ++n) { f32x4 z = {0.f,0.f,0.f,0.f}; acc[m][n] = z; }

#define GEMM_KLOOP \
  GSTAGE(0, 0); \
  __syncthreads(); \
  { int cur = 0; \
    for (int k0 = 0; k0 < K; k0 += 64) { \
      if (k0 + 64 < K) GSTAGE(cur ^ 1, k0 + 64); \
      GEMM_COMPUTE(cur); \
      __syncthreads(); \
      cur ^= 1; \
    } }

// ---------------- Fused QK GEMM (dbuf 2ph): A[8192,1024] * Wqk[2048,1024]^T ----------
// grid (16,64) = 1024 blocks -> exactly 2 rounds at 2 blocks/CU.
// Q/K -> (B,H,S,DK) bf16
__global__ __launch_bounds__(256) void gemm_qk(const unsigned short* __restrict__ A,
                                               const unsigned short* __restrict__ W,
                                               unsigned short* __restrict__ Qo,
                                               unsigned short* __restrict__ Ko) {
  const int K = 1024;
  int bn = blockIdx.x;       // 0..15 (0-7 Q, 8-15 K)
  int bm = blockIdx.y;       // 0..63
  GEMM_PROLOG
  const char* Ab = (const char*)A + (size_t)bm * 128 * (K*2);
  const char* Bb = (const char*)W + (size_t)bn * 128 * (K*2);
  GEMM_KLOOP

  unsigned short* Out = (bn < 8) ? Qo : Ko;
#pragma unroll
  for (int m = 0; m < 4; ++m)
#pragma unroll
    for (int n = 0; n < 4; ++n)
#pragma unroll
      for (int r = 0; r < 4; ++r) {
        int row = bm*128 + wr*64 + m*16 + lgrp*4 + r;
        int cc = (bn & 7)*128 + wc*64 + n*16 + ln15;
        int b = row >> 11, s = row & (S_-1);
        int h = cc >> 6, dk = cc & 63;
        Out[(((size_t)(b*H_ + h)*S_ + s) << 6) + dk] = f2bf(acc[m][n][r]);
      }
}

// ---------------- V GEMM (dbuf 2ph): A[8192,1024] * Wv[1024,1024]^T -> V^T ----------
// grid 512 = 1 round at 2 blocks/CU. V -> (B,H,DK,S) bf16
__global__ __launch_bounds__(256) void gemm_v(const unsigned short* __restrict__ A,
                                              const unsigned short* __restrict__ W,
                                              unsigned short* __restrict__ Vo) {
  const int K = 1024;
  int bx = blockIdx.x;
  int bm = bx >> 3, bn = bx & 7;
  GEMM_PROLOG
  const char* Ab = (const char*)A + (size_t)bm * 128 * (K*2);
  const char* Bb = (const char*)W + (size_t)bn * 128 * (K*2);
  GEMM_KLOOP

#pragma unroll
  for (int m = 0; m < 4; ++m)
#pragma unroll
    for (int n = 0; n < 4; ++n)
#pragma unroll
      for (int r = 0; r < 4; ++r) {
        int row = bm*128 + wr*64 + m*16 + lgrp*4 + r;
        int cc = bn*128 + wc*64 + n*16 + ln15;
        int b = row >> 11, s = row & (S_-1);
        int h = cc >> 6, dk = cc & 63;
        Vo[(((size_t)(b*H_ + h)*DK_ + dk) * S_) + s] = f2bf(acc[m][n][r]);
      }
}

// ---------------- Final GEMM (dbuf 2ph): C[M,N] fp32 = A[M,K]bf16 * W[N,K]^T --------
__global__ __launch_bounds__(256) void gemm_out(const unsigned short* __restrict__ A,
                                                const unsigned short* __restrict__ W,
                                                float* __restrict__ Out) {
  const int K = 1024, N = 1024;
  int bx = blockIdx.x;
  int bm = bx >> 3, bn = bx & 7;
  GEMM_PROLOG
  const char* Ab = (const char*)A + (size_t)bm * 128 * (K*2);
  const char* Bb = (const char*)W + (size_t)bn * 128 * (K*2);
  GEMM_KLOOP

#pragma unroll
  for (int m = 0; m < 4; ++m)
#pragma unroll
    for (int n = 0; n < 4; ++n)
#pragma unroll
      for (int r = 0; r < 4; ++r) {
        int row = bm*128 + wr*64 + m*16 + lgrp*4 + r;
        int col = bn*128 + wc*64 + n*16 + ln15;
        Out[(size_t)row * N + col] = acc[m][n][r];
      }
}

// ---------------- RoPE on Q (scaled 1/8) and K, one launch, 16B/thread ----------------
__global__ void rope_kernel(unsigned short* __restrict__ Qb, unsigned short* __restrict__ Kb,
                            const int* __restrict__ pos) {
  int idx = blockIdx.x * 256 + threadIdx.x;     // [0, 2^21)
  int g = idx & 1048575;
  unsigned short* base = (idx >> 20) ? Kb : Qb;
  float scale = (idx >> 20) ? 1.0f : 0.125f;
  int jb = g & 7;                 // 8-bf16 group within the 64-dk row
  int s = (g >> 3) & (S_-1);
  int bh = g >> 14;
  unsigned short* p = base + (((size_t)bh * S_ + s) << 6) + jb*8;
  short8 v = *(short8*)p;
  float ps = (float)pos[s];
#pragma unroll
  for (int jj = 0; jj < 4; ++jj) {
    int j = jb*4 + jj;
    float freq = exp2f(-(float)j * (13.287712379549449f / 32.0f));
    float ang = ps * freq;
    float sn, cs;
    sincosf(ang, &sn, &cs);
    float x1 = bf2f((unsigned short)v[2*jj]), x2 = bf2f((unsigned short)v[2*jj+1]);
    v[2*jj]   = (short)f2bf((x1*cs - x2*sn) * scale);
    v[2*jj+1] = (short)f2bf((x1*sn + x2*cs) * scale);
  }
  *(short8*)p = v;
}

// ---------------- Flash attention, swapped-operand 32x32 structure (R3) -------------
// Q,K: (B,H,S,DK) bf16 (Q pre-scaled 1/8) ; VT: (B,H,DK,S) bf16 ; O: (B,S,D) bf16
// Block = 128 Q rows (4 waves x 32), KV tiles 64, dbuf staging, heavy-first.
__global__ __launch_bounds__(256) void attn_kernel(const unsigned short* __restrict__ Q,
                                                   const unsigned short* __restrict__ Kg,
                                                   const unsigned short* __restrict__ VT,
                                                   unsigned short* __restrict__ O) {
  const float L2E = 1.4426950408889634f;
  int bid = blockIdx.x;
  int bh = bid & 63;
  int qt = 15 - (bid >> 6);          // heavy blocks first
  int b = bh >> 4, h = bh & 15;
  const int qbase = qt * 128;
  const unsigned short* Qp = Q + (((size_t)bh * S_ + qbase) << 6);
  const char* Kp = (const char*)(Kg + ((size_t)bh * S_ << 6));
  const char* Vp = (const char*)(VT + (size_t)bh * DK_ * S_);

  __shared__ __align__(16) char lK[2][64*128];   // [kv][dk] bf16, swizzled
  __shared__ __align__(16) char lV[2][64*128];   // [dk][kv] bf16, swizzled

  int t = threadIdx.x, wave = t >> 6, lane = t & 63;
  int ln31 = lane & 31, hi = lane >> 5;
  int qw = wave * 32;
  int qg = qbase + qw + ln31;        // this lane's q row

  // Q fragments (B-operand): row q = ln31, k = kk*16 + hi*8 + [0,8)
  short8 qf[4];
#pragma unroll
  for (int kk = 0; kk < 4; ++kk)
    qf[kk] = *(const short8*)(Qp + (size_t)(qw + ln31)*64 + kk*16 + hi*8);

  f32x16 oc[2];
#pragma unroll
  for (int dh = 0; dh < 2; ++dh)
#pragma unroll
    for (int r = 0; r < 16; ++r) oc[dh][r] = 0.f;
  float mi = -__builtin_inff(), li = 0.f;

  const int nt = 2*qt + 2;           // kv tiles

#define STAGE_KV(bufi, ktv) do { \
    _Pragma("unroll") \
    for (int i_ = 0; i_ < 2; ++i_) { \
      int ch_ = i_*256 + t; \
      int a_ = ch_ << 4; \
      int r_ = a_ >> 7; \
      int cb_ = (a_ & 127) ^ ((r_ & 7) << 4); \
      GLDS16(Kp + (size_t)((ktv)*64 + r_)*128 + cb_, lK[bufi] + a_); \
      GLDS16(Vp + (size_t)r_*(S_*2) + (size_t)(ktv)*128 + cb_, lV[bufi] + a_); \
    } \
  } while (0)

  STAGE_KV(0, 0);
  __syncthreads();

  int cur = 0;
  for (int kt = 0; kt < nt; ++kt) {
    if (kt + 1 < nt) STAGE_KV(cur ^ 1, kt + 1);

    const char* cK = lK[cur];
    const char* cV = lV[cur];
    bool active = (kt*64 <= qbase + qw + 31);          // wave-uniform
    bool diag   = (kt*64 + 63 > qbase + qw);           // wave-uniform

    if (active) {
      // ---- QK^T (swapped): sc[t2] = D[kv_local][q] ----
      f32x16 sc[2];
      __builtin_amdgcn_s_setprio(1);
#pragma unroll
      for (int t2 = 0; t2 < 2; ++t2) {
        f32x16 a;
#pragma unroll
        for (int r = 0; r < 16; ++r) a[r] = 0.f;
        int rK = t2*32 + ln31;
        int swz = (rK & 7) << 4;
#pragma unroll
        for (int kk = 0; kk < 4; ++kk) {
          short8 kfr = *(const short8*)(cK + rK*128 + ((kk*32 + hi*16) ^ swz));
          a = __builtin_amdgcn_mfma_f32_32x32x16_bf16(kfr, qf[kk], a, 0, 0, 0);
        }
        sc[t2] = a;
      }
      __builtin_amdgcn_s_setprio(0);

      if (diag) {
#pragma unroll
        for (int t2 = 0; t2 < 2; ++t2)
#pragma unroll
          for (int r = 0; r < 16; ++r) {
            int kv = kt*64 + t2*32 + (r & 3) + 8*(r >> 2) + 4*hi;
            if (kv > qg) sc[t2][r] = -__builtin_inff();
          }
      }

      // ---- in-register softmax: row lives in this lane (+ partner lane^32) ----
      float mx = sc[0][0];
#pragma unroll
      for (int r = 1; r < 16; ++r) mx = fmaxf(mx, sc[0][r]);
#pragma unroll
      for (int r = 0; r < 16; ++r) mx = fmaxf(mx, sc[1][r]);
      mx = fmaxf(mx, __shfl_xor(mx, 32));

      if (!__all(mx - mi <= 8.f)) {          // defer-max (T13)
        float mn = fmaxf(mi, mx);
        float corr = exp2f((mi - mn) * L2E);
        li *= corr;
#pragma unroll
        for (int dh = 0; dh < 2; ++dh)
#pragma unroll
          for (int r = 0; r < 16; ++r) oc[dh][r] *= corr;
        mi = mn;
      }

      float ls = 0.f;
#pragma unroll
      for (int t2 = 0; t2 < 2; ++t2)
#pragma unroll
        for (int r = 0; r < 16; ++r) {
          float pv = exp2f((sc[t2][r] - mi) * L2E);
          sc[t2][r] = pv; ls += pv;
        }
      li += ls;

      // ---- P -> bf16 frags in-register (T12) + PV (swapped) ----
#pragma unroll
      for (int kk = 0; kk < 4; ++kk) {
        int base = 8*(kk & 1), tt = kk >> 1;
        unsigned P0 = cvtpk_bf16(sc[tt][base+0], sc[tt][base+1]);
        unsigned P1 = cvtpk_bf16(sc[tt][base+2], sc[tt][base+3]);
        unsigned Q0 = cvtpk_bf16(sc[tt][base+4], sc[tt][base+5]);
        unsigned Q1 = cvtpk_bf16(sc[tt][base+6], sc[tt][base+7]);
        u32x2 r01 = __builtin_amdgcn_permlane32_swap(P0, Q0, false, false);
        u32x2 s01 = __builtin_amdgcn_permlane32_swap(P1, Q1, false, false);
        union { unsigned u[4]; short8 s8; } pf;
        pf.u[0] = r01[0]; pf.u[1] = s01[0]; pf.u[2] = r01[1]; pf.u[3] = s01[1];
        __builtin_amdgcn_s_setprio(1);
#pragma unroll
        for (int dh = 0; dh < 2; ++dh) {
          int rV = dh*32 + ln31;
          short8 vfr = *(const short8*)(cV + rV*128 + (((kk*32 + hi*16)) ^ ((rV & 7) << 4)));
          oc[dh] = __builtin_amdgcn_mfma_f32_32x32x16_bf16(vfr, pf.s8, oc[dh], 0, 0, 0);
        }
        __builtin_amdgcn_s_setprio(0);
      }
    }

    __syncthreads();
    cur ^= 1;
  }
#undef STAGE_KV

  // ---- epilogue: combine li with partner lane, normalize, store ----
  float lf = li + __shfl_xor(li, 32);
  float rinv = 1.0f / lf;
#pragma unroll
  for (int dh = 0; dh < 2; ++dh)
#pragma unroll
    for (int rg = 0; rg < 4; ++rg) {
      ushort4 pk4;
      pk4.x = f2bf(oc[dh][rg*4+0] * rinv);
      pk4.y = f2bf(oc[dh][rg*4+1] * rinv);
      pk4.z = f2bf(oc[dh][rg*4+2] * rinv);
      pk4.w = f2bf(oc[dh][rg*4+3] * rinv);
      int dk = dh*32 + 8*rg + 4*hi;
      *(ushort4*)(O + (((size_t)(b*S_ + qg)) << 10) + h*64 + dk) = pk4;
    }
}

extern "C" void kernel_launch(void* const* d_in, const int* in_sizes, int n_in,
                              void* d_out, int out_size, void* d_ws, size_t ws_size,
                              hipStream_t stream) {
  const float* x  = (const float*)d_in[0];
  const float* Wq = (const float*)d_in[1];
  const float* Wk = (const float*)d_in[2];
  const float* Wv = (const float*)d_in[3];
  const float* Wo = (const float*)d_in[4];
  const int* pos  = (const int*)d_in[5];

  char* ws = (char*)d_ws;
  unsigned short* xb  = (unsigned short*)(ws + 0);          // 16 MB, also reused as O
  unsigned short* wqb = (unsigned short*)(ws + 16777216);   // wq,wk contiguous (QK fuse)
  unsigned short* wkb = (unsigned short*)(ws + 18874368);
  unsigned short* wvb = (unsigned short*)(ws + 20971520);
  unsigned short* wob = (unsigned short*)(ws + 23068672);
  unsigned short* Qb  = (unsigned short*)(ws + 25165824);   // 16 MB
  unsigned short* Kb  = (unsigned short*)(ws + 41943040);   // 16 MB
  unsigned short* VTb = (unsigned short*)(ws + 58720256);   // 16 MB
  unsigned short* Ob  = xb;  // alias: xb dead after V projection (stream-ordered)

  cvt_kernel<<<8192, 256, 0, stream>>>(x, xb, 2097152);
  cvt_w_kernel<<<4096, 256, 0, stream>>>(Wq, Wk, Wv, Wo, wqb, wkb, wvb, wob);

  gemm_qk<<<dim3(16, 64), 256, 0, stream>>>(xb, wqb, Qb, Kb);   // 1024 blocks, 2 exact rounds
  gemm_v<<<512, 256, 0, stream>>>(xb, wvb, VTb);                // 512 blocks, 1 exact round

  rope_kernel<<<8192, 256, 0, stream>>>(Qb, Kb, pos);   // Q scaled 1/8 inside

  attn_kernel<<<1024, 256, 0, stream>>>(Qb, Kb, VTb, Ob);

  gemm_out<<<512, 256, 0, stream>>>(Ob, wob, (float*)d_out);
}

// Round 7
// 180.515 us; speedup vs baseline: 1.2953x; 1.1044x over previous
//
#include <hip/hip_runtime.h>
#include <stdint.h>

#define B_ 4
#define S_ 2048
#define D_ 1024
#define H_ 16
#define DK_ 64
#define M_ (B_*S_)   // 8192

typedef __attribute__((ext_vector_type(8))) short short8;
typedef __attribute__((ext_vector_type(4))) float f32x4;
typedef __attribute__((ext_vector_type(16))) float f32x16;
typedef __attribute__((ext_vector_type(2))) unsigned int u32x2;

static __device__ __forceinline__ float bf2f(unsigned short s) {
  union { unsigned u; float f; } v; v.u = ((unsigned)s) << 16; return v.f;
}
static __device__ __forceinline__ unsigned short f2bf(float f) {
  union { float f; unsigned u; } v; v.f = f;
  unsigned r = v.u + 0x7fffu + ((v.u >> 16) & 1u);
  return (unsigned short)(r >> 16);
}
static __device__ __forceinline__ unsigned cvtpk_bf16(float lo, float hi) {
  unsigned r;
  asm("v_cvt_pk_bf16_f32 %0, %1, %2" : "=v"(r) : "v"(lo), "v"(hi));
  return r;
}

#define GLDS16(g, l) __builtin_amdgcn_global_load_lds( \
    (const __attribute__((address_space(1))) unsigned int*)(g), \
    (__attribute__((address_space(3))) unsigned int*)(l), 16, 0, 0)

// ---------------- fp32 -> bf16 convert (x) ----------------
__global__ void cvt_kernel(const float* __restrict__ in, unsigned short* __restrict__ out, int n4) {
  int i = blockIdx.x * 256 + threadIdx.x;
  if (i >= n4) return;
  float4 v = ((const float4*)in)[i];
  ushort4 o;
  o.x = f2bf(v.x); o.y = f2bf(v.y); o.z = f2bf(v.z); o.w = f2bf(v.w);
  ((ushort4*)out)[i] = o;
}

// ---------------- fp32 -> bf16 convert (all 4 weights, one launch) ----------------
__global__ void cvt_w_kernel(const float* __restrict__ w0, const float* __restrict__ w1,
                             const float* __restrict__ w2, const float* __restrict__ w3,
                             unsigned short* __restrict__ o0, unsigned short* __restrict__ o1,
                             unsigned short* __restrict__ o2, unsigned short* __restrict__ o3) {
  int idx = blockIdx.x * 256 + threadIdx.x;     // [0, 4*262144)
  int w = idx >> 18, i = idx & 262143;
  const float* src = (w == 0) ? w0 : (w == 1) ? w1 : (w == 2) ? w2 : w3;
  unsigned short* dst = (w == 0) ? o0 : (w == 1) ? o1 : (w == 2) ? o2 : o3;
  float4 v = ((const float4*)src)[i];
  ushort4 o;
  o.x = f2bf(v.x); o.y = f2bf(v.y); o.z = f2bf(v.z); o.w = f2bf(v.w);
  ((ushort4*)dst)[i] = o;
}

// ---- shared GEMM staging macro: stage 128x64 bf16 tiles of A and B (dbuf) ----
#define GSTAGE(bufi, k0v) do { \
    _Pragma("unroll") \
    for (int i_ = 0; i_ < 4; ++i_) { \
      int a_ = (i_*256 + t) << 4; \
      int r_ = a_ >> 7; \
      int cb_ = (a_ & 127) ^ ((r_ & 7) << 4); \
      GLDS16(Ab + (size_t)r_*(K*2) + (size_t)(k0v)*2 + cb_, lA[bufi] + a_); \
      GLDS16(Bb + (size_t)r_*(K*2) + (size_t)(k0v)*2 + cb_, lB[bufi] + a_); \
    } \
  } while (0)

#define GEMM_COMPUTE(bufi) do { \
    const char* cA_ = lA[bufi]; \
    const char* cB_ = lB[bufi]; \
    _Pragma("unroll") \
    for (int kf = 0; kf < 2; ++kf) { \
      int cb = kf*64 + lgrp*16; \
      short8 af[4], bfr[4]; \
      _Pragma("unroll") \
      for (int m = 0; m < 4; ++m) { \
        int r = wr*64 + m*16 + ln15; \
        af[m] = *(const short8*)(cA_ + r*128 + (cb ^ ((r & 7) << 4))); \
      } \
      _Pragma("unroll") \
      for (int n = 0; n < 4; ++n) { \
        int r = wc*64 + n*16 + ln15; \
        bfr[n] = *(const short8*)(cB_ + r*128 + (cb ^ ((r & 7) << 4))); \
      } \
      __builtin_amdgcn_s_setprio(1); \
      _Pragma("unroll") \
      for (int m = 0; m < 4; ++m) \
        _Pragma("unroll") \
        for (int n = 0; n < 4; ++n) \
          acc[m][n] = __builtin_amdgcn_mfma_f32_16x16x32_bf16(af[m], bfr[n], acc[m][n], 0, 0, 0); \
      __builtin_amdgcn_s_setprio(0); \
    } \
  } while (0)

#define GEMM_PROLOG \
  __shared__ __align__(16) char lA[2][128*128]; \
  __shared__ __align__(16) char lB[2][128*128]; \
  int t = threadIdx.x; \
  int wave = t >> 6, lane = t & 63; \
  int ln15 = lane & 15, lgrp = lane >> 4; \
  int wr = wave >> 1, wc = wave & 1; \
  f32x4 acc[4][4]; \
  _Pragma("unroll") \
  for (int m = 0; m < 4; ++m) \
    _Pragma("unroll") \
    for (int n = 0; n < 4; ++n) { f32x4 z = {0.f,0.f,0.f,0.f}; acc[m][n] = z; }

#define GEMM_KLOOP \
  GSTAGE(0, 0); \
  __syncthreads(); \
  { int cur = 0; \
    for (int k0 = 0; k0 < K; k0 += 64) { \
      if (k0 + 64 < K) GSTAGE(cur ^ 1, k0 + 64); \
      GEMM_COMPUTE(cur); \
      __syncthreads(); \
      cur ^= 1; \
    } }

// ---------------- Fused QK GEMM (dbuf 2ph): A[8192,1024] * Wqk[2048,1024]^T ----------
__global__ __launch_bounds__(256) void gemm_qk(const unsigned short* __restrict__ A,
                                               const unsigned short* __restrict__ W,
                                               unsigned short* __restrict__ Qo,
                                               unsigned short* __restrict__ Ko) {
  const int K = 1024;
  int bn = blockIdx.x;       // 0..15 (0-7 Q, 8-15 K)
  int bm = blockIdx.y;       // 0..63
  GEMM_PROLOG
  const char* Ab = (const char*)A + (size_t)bm * 128 * (K*2);
  const char* Bb = (const char*)W + (size_t)bn * 128 * (K*2);
  GEMM_KLOOP

  unsigned short* Out = (bn < 8) ? Qo : Ko;
#pragma unroll
  for (int m = 0; m < 4; ++m)
#pragma unroll
    for (int n = 0; n < 4; ++n)
#pragma unroll
      for (int r = 0; r < 4; ++r) {
        int row = bm*128 + wr*64 + m*16 + lgrp*4 + r;
        int cc = (bn & 7)*128 + wc*64 + n*16 + ln15;
        int b = row >> 11, s = row & (S_-1);
        int h = cc >> 6, dk = cc & 63;
        Out[(((size_t)(b*H_ + h)*S_ + s) << 6) + dk] = f2bf(acc[m][n][r]);
      }
}

// ---------------- V GEMM (dbuf 2ph): A[8192,1024] * Wv[1024,1024]^T -> V^T ----------
__global__ __launch_bounds__(256) void gemm_v(const unsigned short* __restrict__ A,
                                              const unsigned short* __restrict__ W,
                                              unsigned short* __restrict__ Vo) {
  const int K = 1024;
  int bx = blockIdx.x;
  int bm = bx >> 3, bn = bx & 7;
  GEMM_PROLOG
  const char* Ab = (const char*)A + (size_t)bm * 128 * (K*2);
  const char* Bb = (const char*)W + (size_t)bn * 128 * (K*2);
  GEMM_KLOOP

#pragma unroll
  for (int m = 0; m < 4; ++m)
#pragma unroll
    for (int n = 0; n < 4; ++n)
#pragma unroll
      for (int r = 0; r < 4; ++r) {
        int row = bm*128 + wr*64 + m*16 + lgrp*4 + r;
        int cc = bn*128 + wc*64 + n*16 + ln15;
        int b = row >> 11, s = row & (S_-1);
        int h = cc >> 6, dk = cc & 63;
        Vo[(((size_t)(b*H_ + h)*DK_ + dk) * S_) + s] = f2bf(acc[m][n][r]);
      }
}

// ---------------- Final GEMM (dbuf 2ph): C[M,N] fp32 = A[M,K]bf16 * W[N,K]^T --------
__global__ __launch_bounds__(256) void gemm_out(const unsigned short* __restrict__ A,
                                                const unsigned short* __restrict__ W,
                                                float* __restrict__ Out) {
  const int K = 1024, N = 1024;
  int bx = blockIdx.x;
  int bm = bx >> 3, bn = bx & 7;
  GEMM_PROLOG
  const char* Ab = (const char*)A + (size_t)bm * 128 * (K*2);
  const char* Bb = (const char*)W + (size_t)bn * 128 * (K*2);
  GEMM_KLOOP

#pragma unroll
  for (int m = 0; m < 4; ++m)
#pragma unroll
    for (int n = 0; n < 4; ++n)
#pragma unroll
      for (int r = 0; r < 4; ++r) {
        int row = bm*128 + wr*64 + m*16 + lgrp*4 + r;
        int col = bn*128 + wc*64 + n*16 + ln15;
        Out[(size_t)row * N + col] = acc[m][n][r];
      }
}

// ---------------- RoPE on Q (scaled 1/8 * log2e) and K, one launch ----------------
// Q gets 0.125*log2(e) so attention scores are already in exp2 domain.
__global__ void rope_kernel(unsigned short* __restrict__ Qb, unsigned short* __restrict__ Kb,
                            const int* __restrict__ pos) {
  int idx = blockIdx.x * 256 + threadIdx.x;     // [0, 2^21)
  int g = idx & 1048575;
  unsigned short* base = (idx >> 20) ? Kb : Qb;
  float scale = (idx >> 20) ? 1.0f : (0.125f * 1.4426950408889634f);
  int jb = g & 7;                 // 8-bf16 group within the 64-dk row
  int s = (g >> 3) & (S_-1);
  int bh = g >> 14;
  unsigned short* p = base + (((size_t)bh * S_ + s) << 6) + jb*8;
  short8 v = *(short8*)p;
  float ps = (float)pos[s];
#pragma unroll
  for (int jj = 0; jj < 4; ++jj) {
    int j = jb*4 + jj;
    float freq = exp2f(-(float)j * (13.287712379549449f / 32.0f));
    float ang = ps * freq;
    float sn, cs;
    sincosf(ang, &sn, &cs);
    float x1 = bf2f((unsigned short)v[2*jj]), x2 = bf2f((unsigned short)v[2*jj+1]);
    v[2*jj]   = (short)f2bf((x1*cs - x2*sn) * scale);
    v[2*jj+1] = (short)f2bf((x1*sn + x2*cs) * scale);
  }
  *(short8*)p = v;
}

// ---------------- Flash attention, swapped 32x32, 3-buffer counted-vmcnt pipeline ---
// Q,K: (B,H,S,DK) bf16 (Q pre-scaled 1/8*log2e) ; VT: (B,H,DK,S) bf16 ; O: (B,S,D) bf16
// Block = 128 Q rows (4 waves x 32), KV tiles 64, 2-deep prefetch, heavy-first.
// Scores are in log2 domain (exp2 softmax).
__global__ __launch_bounds__(256) void attn_kernel(const unsigned short* __restrict__ Q,
                                                   const unsigned short* __restrict__ Kg,
                                                   const unsigned short* __restrict__ VT,
                                                   unsigned short* __restrict__ O) {
  int bid = blockIdx.x;
  int bh = bid & 63;
  int qt = 15 - (bid >> 6);          // heavy blocks first
  int b = bh >> 4, h = bh & 15;
  const int qbase = qt * 128;
  const unsigned short* Qp = Q + (((size_t)bh * S_ + qbase) << 6);
  const char* Kp = (const char*)(Kg + ((size_t)bh * S_ << 6));
  const char* Vp = (const char*)(VT + (size_t)bh * DK_ * S_);

  __shared__ __align__(16) char lK[3][64*128];   // [kv][dk] bf16, swizzled, 3-buf
  __shared__ __align__(16) char lV[3][64*128];   // [dk][kv] bf16, swizzled, 3-buf

  int t = threadIdx.x, wave = t >> 6, lane = t & 63;
  int ln31 = lane & 31, hi = lane >> 5;
  int qw = wave * 32;
  int qg = qbase + qw + ln31;        // this lane's q row

  // Q fragments (B-operand): row q = ln31, k = kk*16 + hi*8 + [0,8)
  short8 qf[4];
#pragma unroll
  for (int kk = 0; kk < 4; ++kk)
    qf[kk] = *(const short8*)(Qp + (size_t)(qw + ln31)*64 + kk*16 + hi*8);

  f32x16 oc[2];
#pragma unroll
  for (int dh = 0; dh < 2; ++dh)
#pragma unroll
    for (int r = 0; r < 16; ++r) oc[dh][r] = 0.f;
  float mi = -__builtin_inff(), li = 0.f;

  const int nt = 2*qt + 2;           // kv tiles (>= 2 always)

#define STAGE_KV(kbuf, vbuf, ktv) do { \
    _Pragma("unroll") \
    for (int i_ = 0; i_ < 2; ++i_) { \
      int ch_ = i_*256 + t; \
      int a_ = ch_ << 4; \
      int r_ = a_ >> 7; \
      int cb_ = (a_ & 127) ^ ((r_ & 7) << 4); \
      GLDS16(Kp + (size_t)((ktv)*64 + r_)*128 + cb_, (kbuf) + a_); \
      GLDS16(Vp + (size_t)r_*(S_*2) + (size_t)(ktv)*128 + cb_, (vbuf) + a_); \
    } \
  } while (0)

  // 3-buffer rotation: a = compute, b = landing (kt+1), c = staging (kt+2)
  char *Ka = lK[0], *Kb_ = lK[1], *Kc = lK[2];
  char *Va = lV[0], *Vb = lV[1], *Vc = lV[2];

  STAGE_KV(Ka, Va, 0);
  STAGE_KV(Kb_, Vb, 1);
  asm volatile("s_waitcnt vmcnt(4)" ::: "memory");   // buf a landed (b's 4 may fly)
  __builtin_amdgcn_s_barrier();

  for (int kt = 0; kt < nt; ++kt) {
    bool more = (kt + 2 < nt);
    if (more) STAGE_KV(Kc, Vc, kt + 2);    // 2-deep prefetch: lands under 2 tiles of compute

    const char* cK = Ka;
    const char* cV = Va;
    bool active = (kt*64 <= qbase + qw + 31);          // wave-uniform
    bool diag   = (kt*64 + 63 > qbase + qw);           // wave-uniform

    if (active) {
      // ---- QK^T (swapped): sc[t2] = D[kv_local][q], log2-domain scores ----
      f32x16 sc[2];
      __builtin_amdgcn_s_setprio(1);
#pragma unroll
      for (int t2 = 0; t2 < 2; ++t2) {
        f32x16 a;
#pragma unroll
        for (int r = 0; r < 16; ++r) a[r] = 0.f;
        int rK = t2*32 + ln31;
        int swz = (rK & 7) << 4;
#pragma unroll
        for (int kk = 0; kk < 4; ++kk) {
          short8 kfr = *(const short8*)(cK + rK*128 + ((kk*32 + hi*16) ^ swz));
          a = __builtin_amdgcn_mfma_f32_32x32x16_bf16(kfr, qf[kk], a, 0, 0, 0);
        }
        sc[t2] = a;
      }
      __builtin_amdgcn_s_setprio(0);

      if (diag) {
#pragma unroll
        for (int t2 = 0; t2 < 2; ++t2)
#pragma unroll
          for (int r = 0; r < 16; ++r) {
            int kv = kt*64 + t2*32 + (r & 3) + 8*(r >> 2) + 4*hi;
            if (kv > qg) sc[t2][r] = -__builtin_inff();
          }
      }

      // ---- in-register softmax (exp2 domain), 4-chain tree reductions ----
      float mm[4];
#pragma unroll
      for (int j = 0; j < 4; ++j) mm[j] = fmaxf(sc[0][j], sc[1][j]);
#pragma unroll
      for (int r = 4; r < 16; ++r) mm[r & 3] = fmaxf(mm[r & 3], fmaxf(sc[0][r], sc[1][r]));
      float mx = fmaxf(fmaxf(mm[0], mm[1]), fmaxf(mm[2], mm[3]));
      mx = fmaxf(mx, __shfl_xor(mx, 32));

      if (!__all(mx - mi <= 8.f)) {          // defer-max (T13), 2^8 bound
        float mn = fmaxf(mi, mx);
        float corr = __builtin_amdgcn_exp2f(mi - mn);
        li *= corr;
#pragma unroll
        for (int dh = 0; dh < 2; ++dh)
#pragma unroll
          for (int r = 0; r < 16; ++r) oc[dh][r] *= corr;
        mi = mn;
      }

      float lss[4] = {0.f, 0.f, 0.f, 0.f};
#pragma unroll
      for (int t2 = 0; t2 < 2; ++t2)
#pragma unroll
        for (int r = 0; r < 16; ++r) {
          float pv = __builtin_amdgcn_exp2f(sc[t2][r] - mi);
          sc[t2][r] = pv; lss[r & 3] += pv;
        }
      li += (lss[0] + lss[1]) + (lss[2] + lss[3]);

      // ---- P -> bf16 frags in-register (T12) + PV (swapped) ----
#pragma unroll
      for (int kk = 0; kk < 4; ++kk) {
        int base = 8*(kk & 1), tt = kk >> 1;
        unsigned P0 = cvtpk_bf16(sc[tt][base+0], sc[tt][base+1]);
        unsigned P1 = cvtpk_bf16(sc[tt][base+2], sc[tt][base+3]);
        unsigned Q0 = cvtpk_bf16(sc[tt][base+4], sc[tt][base+5]);
        unsigned Q1 = cvtpk_bf16(sc[tt][base+6], sc[tt][base+7]);
        u32x2 r01 = __builtin_amdgcn_permlane32_swap(P0, Q0, false, false);
        u32x2 s01 = __builtin_amdgcn_permlane32_swap(P1, Q1, false, false);
        union { unsigned u[4]; short8 s8; } pf;
        pf.u[0] = r01[0]; pf.u[1] = s01[0]; pf.u[2] = r01[1]; pf.u[3] = s01[1];
        __builtin_amdgcn_s_setprio(1);
#pragma unroll
        for (int dh = 0; dh < 2; ++dh) {
          int rV = dh*32 + ln31;
          short8 vfr = *(const short8*)(cV + rV*128 + (((kk*32 + hi*16)) ^ ((rV & 7) << 4)));
          oc[dh] = __builtin_amdgcn_mfma_f32_32x32x16_bf16(vfr, pf.s8, oc[dh], 0, 0, 0);
        }
        __builtin_amdgcn_s_setprio(0);
      }
    }

    // counted wait: only kt+1's 4 loads must have landed (issued a full iter ago).
    if (more) asm volatile("s_waitcnt vmcnt(4)" ::: "memory");
    else      asm volatile("s_waitcnt vmcnt(0)" ::: "memory");
    __builtin_amdgcn_s_barrier();

    char* tk = Ka; Ka = Kb_; Kb_ = Kc; Kc = tk;
    char* tv = Va; Va = Vb;  Vb = Vc;  Vc = tv;
  }
#undef STAGE_KV

  // ---- epilogue: combine li with partner lane, normalize, store ----
  float lf = li + __shfl_xor(li, 32);
  float rinv = 1.0f / lf;
#pragma unroll
  for (int dh = 0; dh < 2; ++dh)
#pragma unroll
    for (int rg = 0; rg < 4; ++rg) {
      ushort4 pk4;
      pk4.x = f2bf(oc[dh][rg*4+0] * rinv);
      pk4.y = f2bf(oc[dh][rg*4+1] * rinv);
      pk4.z = f2bf(oc[dh][rg*4+2] * rinv);
      pk4.w = f2bf(oc[dh][rg*4+3] * rinv);
      int dk = dh*32 + 8*rg + 4*hi;
      *(ushort4*)(O + (((size_t)(b*S_ + qg)) << 10) + h*64 + dk) = pk4;
    }
}

extern "C" void kernel_launch(void* const* d_in, const int* in_sizes, int n_in,
                              void* d_out, int out_size, void* d_ws, size_t ws_size,
                              hipStream_t stream) {
  const float* x  = (const float*)d_in[0];
  const float* Wq = (const float*)d_in[1];
  const float* Wk = (const float*)d_in[2];
  const float* Wv = (const float*)d_in[3];
  const float* Wo = (const float*)d_in[4];
  const int* pos  = (const int*)d_in[5];

  char* ws = (char*)d_ws;
  unsigned short* xb  = (unsigned short*)(ws + 0);          // 16 MB, also reused as O
  unsigned short* wqb = (unsigned short*)(ws + 16777216);   // wq,wk contiguous (QK fuse)
  unsigned short* wkb = (unsigned short*)(ws + 18874368);
  unsigned short* wvb = (unsigned short*)(ws + 20971520);
  unsigned short* wob = (unsigned short*)(ws + 23068672);
  unsigned short* Qb  = (unsigned short*)(ws + 25165824);   // 16 MB
  unsigned short* Kb  = (unsigned short*)(ws + 41943040);   // 16 MB
  unsigned short* VTb = (unsigned short*)(ws + 58720256);   // 16 MB
  unsigned short* Ob  = xb;  // alias: xb dead after V projection (stream-ordered)

  cvt_kernel<<<8192, 256, 0, stream>>>(x, xb, 2097152);
  cvt_w_kernel<<<4096, 256, 0, stream>>>(Wq, Wk, Wv, Wo, wqb, wkb, wvb, wob);

  gemm_qk<<<dim3(16, 64), 256, 0, stream>>>(xb, wqb, Qb, Kb);   // 1024 blocks, 2 exact rounds
  gemm_v<<<512, 256, 0, stream>>>(xb, wvb, VTb);                // 512 blocks, 1 exact round

  rope_kernel<<<8192, 256, 0, stream>>>(Qb, Kb, pos);   // Q scaled 1/8*log2e inside

  attn_kernel<<<1024, 256, 0, stream>>>(Qb, Kb, VTb, Ob);

  gemm_out<<<512, 256, 0, stream>>>(Ob, wob, (float*)d_out);
}